// Round 16
// baseline (709.943 us; speedup 1.0000x reference)
//
#include <hip/hip_runtime.h>
#include <hip/hip_bf16.h>
#include <math.h>
#include <float.h>
#include <limits.h>

#define T_ROWS 131072   // 32 * 4096 patches
#define HROWS  65536    // half

typedef __attribute__((ext_vector_type(8))) short short8;
typedef __attribute__((ext_vector_type(4))) float f32x4;

__device__ __forceinline__ float gelu_f(float x){
    return 0.5f * x * (1.0f + erff(x * 0.7071067811865475f));
}
__device__ __forceinline__ ushort f2bf(float f){
    union { float f; unsigned int i; } v; v.f = f;
    unsigned int i = v.i;
    unsigned int r = (i + 0x7fffu + ((i >> 16) & 1u)) >> 16;
    return (ushort)r;
}
// exact 3-way truncation split: x ~= b0+b1+b2 (each bf16), >=24 mantissa bits
__device__ __forceinline__ void split3(float x, ushort &u0, ushort &u1, ushort &u2){
    union { float f; unsigned int i; } v; v.f = x;
    u0 = (ushort)(v.i >> 16);
    union { unsigned int i; float f; } h0; h0.i = ((unsigned int)u0) << 16;
    float r = x - h0.f;                       // exact (Sterbenz)
    union { float f; unsigned int i; } vr; vr.f = r;
    u1 = (ushort)(vr.i >> 16);
    union { unsigned int i; float f; } h1; h1.i = ((unsigned int)u1) << 16;
    float r2 = r - h1.f;                      // exact
    union { float f; unsigned int i; } v2; v2.f = r2;
    u2 = (ushort)(v2.i >> 16);
}

// ---------------------------------------------------------------------------
// Merged prep (unchanged)
// ---------------------------------------------------------------------------
__global__ __launch_bounds__(256) void prep_kernel(
    const float* __restrict__ w2, const float* __restrict__ w3,
    const float* __restrict__ d1, const float* __restrict__ d2,
    const float* __restrict__ w1, const float* __restrict__ b1,
    const float* __restrict__ cb,
    ushort* __restrict__ w2s0, ushort* __restrict__ w2s1, ushort* __restrict__ w2s2,
    ushort* __restrict__ w3s0, ushort* __restrict__ w3s1, ushort* __restrict__ w3s2,
    ushort* __restrict__ w1b, ushort* __restrict__ w2b,
    float* __restrict__ cn, ushort* __restrict__ cbb,
    ushort* __restrict__ cbs0, ushort* __restrict__ cbs1, ushort* __restrict__ cbs2,
    ushort* __restrict__ w1p0, ushort* __restrict__ w1p1, ushort* __restrict__ w1p2,
    float* __restrict__ bias2)
{
    const int blk = blockIdx.x, tid = threadIdx.x;
    if (blk < 64){
        const int i = (blk*256 + tid)*4;
        float4 a = *(const float4*)(w2 + i);
        ushort4 s0, s1, s2;
        split3(a.x, s0.x, s1.x, s2.x); split3(a.y, s0.y, s1.y, s2.y);
        split3(a.z, s0.z, s1.z, s2.z); split3(a.w, s0.w, s1.w, s2.w);
        *(ushort4*)(w2s0+i)=s0; *(ushort4*)(w2s1+i)=s1; *(ushort4*)(w2s2+i)=s2;
        float4 b = *(const float4*)(w3 + i);
        split3(b.x, s0.x, s1.x, s2.x); split3(b.y, s0.y, s1.y, s2.y);
        split3(b.z, s0.z, s1.z, s2.z); split3(b.w, s0.w, s1.w, s2.w);
        *(ushort4*)(w3s0+i)=s0; *(ushort4*)(w3s1+i)=s1; *(ushort4*)(w3s2+i)=s2;
        float4 c = *(const float4*)(d1 + i);
        ushort4 u; u.x=f2bf(c.x); u.y=f2bf(c.y); u.z=f2bf(c.z); u.w=f2bf(c.w);
        *(ushort4*)(w1b+i) = u;
        float4 d = *(const float4*)(d2 + i);
        u.x=f2bf(d.x); u.y=f2bf(d.y); u.z=f2bf(d.z); u.w=f2bf(d.w);
        *(ushort4*)(w2b+i) = u;
    } else if (blk < 192){
        const int lane = tid & 63;
        const int code = (blk-64)*4 + (tid >> 6);
        float4 v = ((const float4*)(cb + (size_t)code*256))[lane];
        size_t off = (size_t)code*256 + lane*4;
        ushort4 u; u.x=f2bf(v.x); u.y=f2bf(v.y); u.z=f2bf(v.z); u.w=f2bf(v.w);
        *(ushort4*)(cbb + off) = u;
        ushort4 s0, s1, s2;
        split3(v.x, s0.x, s1.x, s2.x); split3(v.y, s0.y, s1.y, s2.y);
        split3(v.z, s0.z, s1.z, s2.z); split3(v.w, s0.w, s1.w, s2.w);
        *(ushort4*)(cbs0 + off) = s0;
        *(ushort4*)(cbs1 + off) = s1;
        *(ushort4*)(cbs2 + off) = s2;
        float s = v.x*v.x + v.y*v.y + v.z*v.z + v.w*v.w;
        #pragma unroll
        for (int m=1; m<64; m<<=1) s += __shfl_xor(s, m);
        if (lane == 0) cn[code] = s;
    } else if (blk < 208){
        const int idx = (blk-192)*256 + tid;    // 0..4095
        const int n = idx >> 4, k = (idx & 15)*4;
        ushort4 s0 = {0,0,0,0}, s1 = {0,0,0,0}, s2 = {0,0,0,0};
        if (k < 48){
            float4 v = *(const float4*)(w1 + n*48 + k);
            split3(v.x, s0.x, s1.x, s2.x); split3(v.y, s0.y, s1.y, s2.y);
            split3(v.z, s0.z, s1.z, s2.z); split3(v.w, s0.w, s1.w, s2.w);
        }
        *(ushort4*)(w1p0 + n*64 + k) = s0;
        *(ushort4*)(w1p1 + n*64 + k) = s1;
        *(ushort4*)(w1p2 + n*64 + k) = s2;
    } else {
        float s = 0.0f;
        for (int k=0;k<48;++k) s += w1[tid*48 + k];
        bias2[tid] = b1[tid] - s;
    }
}

// ---------------------------------------------------------------------------
// f32-faithful split6 MFMA GEMM, 64 rows x 256 cols per block (unchanged).
// ---------------------------------------------------------------------------
template<int KTOT, bool GELU, int LOADER, bool SCALE>
__global__ __launch_bounds__(256, 3) void split6_gemm(
    const float* __restrict__ Ain,
    const float* __restrict__ frames,
    const ushort* __restrict__ W0, const ushort* __restrict__ W1,
    const ushort* __restrict__ W2,
    const float* __restrict__ bias,
    float* __restrict__ Cout)
{
    __shared__ __align__(16) ushort Al[3][64][40];
    __shared__ __align__(16) ushort Wl[256][40];

    const int tid = threadIdx.x;
    const int m0 = blockIdx.x * 64;
    const int arow = tid >> 2, q = tid & 3;
    const int lane = tid & 63;
    const int w = tid >> 6;
    const int lr = lane & 15, lg = lane >> 4;

    const float* asrc = nullptr;
    int pbase = 0;
    if constexpr (LOADER == 0){
        asrc = Ain + (size_t)(m0 + arow)*KTOT + q*8;
    } else {
        int p = m0 + arow;
        int b = p >> 12, nl = p & 4095, hh = nl >> 6, ww = nl & 63;
        pbase = ((b*256 + hh*4)*256 + ww*4)*3;
    }
    const ushort* wsrc  = W0 + (size_t)tid*KTOT;
    const ushort* w1frag = W1 + (size_t)(w*64 + lr)*KTOT + lg*8;
    const ushort* w2frag = W2 + (size_t)(w*64 + lr)*KTOT + lg*8;

    f32x4 acc[4][4];
    #pragma unroll
    for (int mi=0;mi<4;++mi)
        #pragma unroll
        for (int ni=0;ni<4;++ni)
            acc[mi][ni] = (f32x4){0.f,0.f,0.f,0.f};

    for (int k0=0; k0<KTOT; k0+=32){
        float x[8];
        if constexpr (LOADER == 0){
            *(float4*)&x[0] = *(const float4*)(asrc + k0);
            *(float4*)&x[4] = *(const float4*)(asrc + k0 + 4);
        } else {
            #pragma unroll
            for (int j=0;j<2;++j){
                int kk = k0 + q*8 + j*4;
                float4 v = {0.f,0.f,0.f,0.f};
                if (kk < 48){
                    int ph = kk/12, rem = kk - ph*12;
                    v = *(const float4*)(frames + pbase + ph*768 + rem);
                }
                x[j*4+0]=v.x; x[j*4+1]=v.y; x[j*4+2]=v.z; x[j*4+3]=v.w;
            }
        }
        ushort t0[8], t1[8], t2[8];
        #pragma unroll
        for (int e=0;e<8;++e) split3(x[e], t0[e], t1[e], t2[e]);
        *(uint4*)&Al[0][arow][q*8] = *(const uint4*)t0;
        *(uint4*)&Al[1][arow][q*8] = *(const uint4*)t1;
        *(uint4*)&Al[2][arow][q*8] = *(const uint4*)t2;
        *(uint4*)&Wl[tid][0]  = *(const uint4*)(wsrc + k0);
        *(uint4*)&Wl[tid][8]  = *(const uint4*)(wsrc + k0 + 8);
        *(uint4*)&Wl[tid][16] = *(const uint4*)(wsrc + k0 + 16);
        *(uint4*)&Wl[tid][24] = *(const uint4*)(wsrc + k0 + 24);
        short8 b1v[4], b2v[4];
        #pragma unroll
        for (int ni=0;ni<4;++ni){
            b1v[ni] = *(const short8*)(w1frag + (size_t)ni*16*KTOT + k0);
            b2v[ni] = *(const short8*)(w2frag + (size_t)ni*16*KTOT + k0);
        }
        __syncthreads();

        short8 b0v[4];
        #pragma unroll
        for (int ni=0;ni<4;++ni)
            b0v[ni] = *(const short8*)&Wl[w*64 + ni*16 + lr][lg*8];
        #pragma unroll
        for (int mi=0;mi<4;++mi){
            short8 a0 = *(const short8*)&Al[0][mi*16 + lr][lg*8];
            short8 a1 = *(const short8*)&Al[1][mi*16 + lr][lg*8];
            short8 a2 = *(const short8*)&Al[2][mi*16 + lr][lg*8];
            #pragma unroll
            for (int ni=0;ni<4;++ni)
                acc[mi][ni] = __builtin_amdgcn_mfma_f32_16x16x32_bf16(a0, b0v[ni], acc[mi][ni], 0,0,0);
            #pragma unroll
            for (int ni=0;ni<4;++ni)
                acc[mi][ni] = __builtin_amdgcn_mfma_f32_16x16x32_bf16(a0, b1v[ni], acc[mi][ni], 0,0,0);
            #pragma unroll
            for (int ni=0;ni<4;++ni)
                acc[mi][ni] = __builtin_amdgcn_mfma_f32_16x16x32_bf16(a1, b0v[ni], acc[mi][ni], 0,0,0);
            #pragma unroll
            for (int ni=0;ni<4;++ni)
                acc[mi][ni] = __builtin_amdgcn_mfma_f32_16x16x32_bf16(a0, b2v[ni], acc[mi][ni], 0,0,0);
            #pragma unroll
            for (int ni=0;ni<4;++ni)
                acc[mi][ni] = __builtin_amdgcn_mfma_f32_16x16x32_bf16(a1, b1v[ni], acc[mi][ni], 0,0,0);
            #pragma unroll
            for (int ni=0;ni<4;++ni)
                acc[mi][ni] = __builtin_amdgcn_mfma_f32_16x16x32_bf16(a2, b0v[ni], acc[mi][ni], 0,0,0);
        }
        __syncthreads();
    }

    const float alpha = 2.0f/255.0f;
    float bn[4];
    #pragma unroll
    for (int ni=0;ni<4;++ni) bn[ni] = bias[w*64 + ni*16 + lr];
    #pragma unroll
    for (int mi=0;mi<4;++mi)
        #pragma unroll
        for (int ni=0;ni<4;++ni)
            #pragma unroll
            for (int r=0;r<4;++r){
                int row = m0 + mi*16 + lg*4 + r;
                float v;
                if (SCALE) v = fmaf(alpha, acc[mi][ni][r], bn[ni]);
                else       v = acc[mi][ni][r] + bn[ni];
                if (GELU) v = gelu_f(v);
                Cout[(size_t)row*256 + w*64 + ni*16 + lr] = v;
            }
}

// ---------------------------------------------------------------------------
// enc3 variant: identical GEMM, epilogue writes the 3 exact bf16 split planes
// of z plus per-row ||z||^2 (no f32 z output). Pointers pre-offset per half.
// ---------------------------------------------------------------------------
__global__ __launch_bounds__(256, 3) void split6_zout(
    const float* __restrict__ Ain,
    const ushort* __restrict__ W0, const ushort* __restrict__ W1,
    const ushort* __restrict__ W2,
    const float* __restrict__ bias,
    ushort* __restrict__ zb0, ushort* __restrict__ zb1, ushort* __restrict__ zb2,
    float* __restrict__ zz_out)
{
    __shared__ __align__(16) ushort Al[3][64][40];
    __shared__ __align__(16) ushort Wl[256][40];
    __shared__ float zs[64][4];

    const int tid = threadIdx.x;
    const int m0 = blockIdx.x * 64;
    const int arow = tid >> 2, q = tid & 3;
    const int lane = tid & 63;
    const int w = tid >> 6;
    const int lr = lane & 15, lg = lane >> 4;

    const float* asrc = Ain + (size_t)(m0 + arow)*256 + q*8;
    const ushort* wsrc  = W0 + (size_t)tid*256;
    const ushort* w1frag = W1 + (size_t)(w*64 + lr)*256 + lg*8;
    const ushort* w2frag = W2 + (size_t)(w*64 + lr)*256 + lg*8;

    f32x4 acc[4][4];
    #pragma unroll
    for (int mi=0;mi<4;++mi)
        #pragma unroll
        for (int ni=0;ni<4;++ni)
            acc[mi][ni] = (f32x4){0.f,0.f,0.f,0.f};

    for (int k0=0; k0<256; k0+=32){
        float x[8];
        *(float4*)&x[0] = *(const float4*)(asrc + k0);
        *(float4*)&x[4] = *(const float4*)(asrc + k0 + 4);
        ushort t0[8], t1[8], t2[8];
        #pragma unroll
        for (int e=0;e<8;++e) split3(x[e], t0[e], t1[e], t2[e]);
        *(uint4*)&Al[0][arow][q*8] = *(const uint4*)t0;
        *(uint4*)&Al[1][arow][q*8] = *(const uint4*)t1;
        *(uint4*)&Al[2][arow][q*8] = *(const uint4*)t2;
        *(uint4*)&Wl[tid][0]  = *(const uint4*)(wsrc + k0);
        *(uint4*)&Wl[tid][8]  = *(const uint4*)(wsrc + k0 + 8);
        *(uint4*)&Wl[tid][16] = *(const uint4*)(wsrc + k0 + 16);
        *(uint4*)&Wl[tid][24] = *(const uint4*)(wsrc + k0 + 24);
        short8 b1v[4], b2v[4];
        #pragma unroll
        for (int ni=0;ni<4;++ni){
            b1v[ni] = *(const short8*)(w1frag + (size_t)ni*16*256 + k0);
            b2v[ni] = *(const short8*)(w2frag + (size_t)ni*16*256 + k0);
        }
        __syncthreads();

        short8 b0v[4];
        #pragma unroll
        for (int ni=0;ni<4;++ni)
            b0v[ni] = *(const short8*)&Wl[w*64 + ni*16 + lr][lg*8];
        #pragma unroll
        for (int mi=0;mi<4;++mi){
            short8 a0 = *(const short8*)&Al[0][mi*16 + lr][lg*8];
            short8 a1 = *(const short8*)&Al[1][mi*16 + lr][lg*8];
            short8 a2 = *(const short8*)&Al[2][mi*16 + lr][lg*8];
            #pragma unroll
            for (int ni=0;ni<4;++ni)
                acc[mi][ni] = __builtin_amdgcn_mfma_f32_16x16x32_bf16(a0, b0v[ni], acc[mi][ni], 0,0,0);
            #pragma unroll
            for (int ni=0;ni<4;++ni)
                acc[mi][ni] = __builtin_amdgcn_mfma_f32_16x16x32_bf16(a0, b1v[ni], acc[mi][ni], 0,0,0);
            #pragma unroll
            for (int ni=0;ni<4;++ni)
                acc[mi][ni] = __builtin_amdgcn_mfma_f32_16x16x32_bf16(a1, b0v[ni], acc[mi][ni], 0,0,0);
            #pragma unroll
            for (int ni=0;ni<4;++ni)
                acc[mi][ni] = __builtin_amdgcn_mfma_f32_16x16x32_bf16(a0, b2v[ni], acc[mi][ni], 0,0,0);
            #pragma unroll
            for (int ni=0;ni<4;++ni)
                acc[mi][ni] = __builtin_amdgcn_mfma_f32_16x16x32_bf16(a1, b1v[ni], acc[mi][ni], 0,0,0);
            #pragma unroll
            for (int ni=0;ni<4;++ni)
                acc[mi][ni] = __builtin_amdgcn_mfma_f32_16x16x32_bf16(a2, b0v[ni], acc[mi][ni], 0,0,0);
        }
        __syncthreads();
    }

    float bn[4];
    #pragma unroll
    for (int ni=0;ni<4;++ni) bn[ni] = bias[w*64 + ni*16 + lr];
    #pragma unroll
    for (int mi=0;mi<4;++mi)
        #pragma unroll
        for (int r=0;r<4;++r){
            int row = m0 + mi*16 + lg*4 + r;
            float p = 0.0f;
            #pragma unroll
            for (int ni=0;ni<4;++ni){
                float v = acc[mi][ni][r] + bn[ni];
                p = fmaf(v, v, p);
                ushort s0, s1, s2;
                split3(v, s0, s1, s2);
                size_t off = (size_t)row*256 + w*64 + ni*16 + lr;
                zb0[off] = s0; zb1[off] = s1; zb2[off] = s2;
            }
            p += __shfl_xor(p, 1); p += __shfl_xor(p, 2);
            p += __shfl_xor(p, 4); p += __shfl_xor(p, 8);
            if (lr == 0) zs[mi*16 + lg*4 + r][w] = p;
        }
    __syncthreads();
    if (tid < 64)
        zz_out[m0 + tid] = zs[tid][0] + zs[tid][1] + zs[tid][2] + zs[tid][3];
}

#define INSERT1(dv, iv) do { \
    float _d = (dv); int _i = (iv); \
    if (_d < bd || (_d == bd && _i < bi)){ bd = _d; bi = _i; } \
} while(0)

// ---------------------------------------------------------------------------
// EXACT distance pass from PRE-SPLIT z planes (no split3, no zz).
// Identical MFMA sequence -> bitwise identical distances. Per-half pointers.
// ---------------------------------------------------------------------------
__global__ __launch_bounds__(256, 3) void tokens_split6_pp(
    const ushort* __restrict__ Z0, const ushort* __restrict__ Z1,
    const ushort* __restrict__ Z2,
    const ushort* __restrict__ C0, const ushort* __restrict__ C1,
    const ushort* __restrict__ C2,
    const float* __restrict__ cn,
    float2* __restrict__ partials)
{
    __shared__ __align__(16) ushort Al[3][128][40];
    __shared__ __align__(16) ushort Wl[2][128][40];
    __shared__ float2 ptop[128][2];

    const int tid = threadIdx.x;
    const int m0 = blockIdx.x * 128;
    const int n0 = blockIdx.y * 128;
    const int srow = tid >> 1, shalf = (tid & 1) * 16;
    const int lane = tid & 63;
    const int w = tid >> 6;
    const int wm = (w >> 1) * 64, wn = (w & 1) * 64;
    const int lr = lane & 15, lg = lane >> 4;

    const size_t arow_off = (size_t)(m0 + srow)*256 + shalf;
    const ushort* ws0  = C0 + (size_t)(n0 + srow)*256 + shalf;
    const ushort* ws1  = C1 + (size_t)(n0 + srow)*256 + shalf;
    const ushort* c2frag = C2 + (size_t)(n0 + wn + lr)*256 + lg*8;

    f32x4 acc[4][4];
    #pragma unroll
    for (int mi=0;mi<4;++mi)
        #pragma unroll
        for (int ni=0;ni<4;++ni)
            acc[mi][ni] = (f32x4){0.f,0.f,0.f,0.f};

    for (int k0=0; k0<256; k0+=32){
        *(uint4*)&Al[0][srow][shalf]   = *(const uint4*)(Z0 + arow_off + k0);
        *(uint4*)&Al[0][srow][shalf+8] = *(const uint4*)(Z0 + arow_off + k0 + 8);
        *(uint4*)&Al[1][srow][shalf]   = *(const uint4*)(Z1 + arow_off + k0);
        *(uint4*)&Al[1][srow][shalf+8] = *(const uint4*)(Z1 + arow_off + k0 + 8);
        *(uint4*)&Al[2][srow][shalf]   = *(const uint4*)(Z2 + arow_off + k0);
        *(uint4*)&Al[2][srow][shalf+8] = *(const uint4*)(Z2 + arow_off + k0 + 8);
        *(uint4*)&Wl[0][srow][shalf]   = *(const uint4*)(ws0 + k0);
        *(uint4*)&Wl[0][srow][shalf+8] = *(const uint4*)(ws0 + k0 + 8);
        *(uint4*)&Wl[1][srow][shalf]   = *(const uint4*)(ws1 + k0);
        *(uint4*)&Wl[1][srow][shalf+8] = *(const uint4*)(ws1 + k0 + 8);
        short8 b2[4];
        #pragma unroll
        for (int ni=0;ni<4;++ni)
            b2[ni] = *(const short8*)(c2frag + (size_t)ni*16*256 + k0);
        __syncthreads();

        short8 b0[4], b1[4];
        #pragma unroll
        for (int ni=0;ni<4;++ni){
            b0[ni] = *(const short8*)&Wl[0][wn + ni*16 + lr][lg*8];
            b1[ni] = *(const short8*)&Wl[1][wn + ni*16 + lr][lg*8];
        }
        #pragma unroll
        for (int mi=0;mi<4;++mi){
            short8 a0 = *(const short8*)&Al[0][wm + mi*16 + lr][lg*8];
            short8 a1 = *(const short8*)&Al[1][wm + mi*16 + lr][lg*8];
            short8 a2 = *(const short8*)&Al[2][wm + mi*16 + lr][lg*8];
            #pragma unroll
            for (int ni=0;ni<4;++ni)
                acc[mi][ni] = __builtin_amdgcn_mfma_f32_16x16x32_bf16(a0, b0[ni], acc[mi][ni], 0,0,0);
            #pragma unroll
            for (int ni=0;ni<4;++ni)
                acc[mi][ni] = __builtin_amdgcn_mfma_f32_16x16x32_bf16(a0, b1[ni], acc[mi][ni], 0,0,0);
            #pragma unroll
            for (int ni=0;ni<4;++ni)
                acc[mi][ni] = __builtin_amdgcn_mfma_f32_16x16x32_bf16(a1, b0[ni], acc[mi][ni], 0,0,0);
            #pragma unroll
            for (int ni=0;ni<4;++ni)
                acc[mi][ni] = __builtin_amdgcn_mfma_f32_16x16x32_bf16(a0, b2[ni], acc[mi][ni], 0,0,0);
            #pragma unroll
            for (int ni=0;ni<4;++ni)
                acc[mi][ni] = __builtin_amdgcn_mfma_f32_16x16x32_bf16(a1, b1[ni], acc[mi][ni], 0,0,0);
            #pragma unroll
            for (int ni=0;ni<4;++ni)
                acc[mi][ni] = __builtin_amdgcn_mfma_f32_16x16x32_bf16(a2, b0[ni], acc[mi][ni], 0,0,0);
        }
        __syncthreads();
    }

    float cnl[4];
    #pragma unroll
    for (int ni=0;ni<4;++ni) cnl[ni] = cn[n0 + wn + ni*16 + lr];

    #pragma unroll
    for (int mi=0;mi<4;++mi)
        #pragma unroll
        for (int r=0;r<4;++r){
            float bd = FLT_MAX; int bi = INT_MAX;
            #pragma unroll
            for (int ni=0;ni<4;++ni){
                float d = cnl[ni] - 2.0f*acc[mi][ni][r];
                int col = n0 + wn + ni*16 + lr;
                INSERT1(d, col);
            }
            #pragma unroll
            for (int m=1; m<16; m<<=1){
                float od = __shfl_xor(bd, m);
                int   oi = __shfl_xor(bi, m);
                INSERT1(od, oi);
            }
            if (lr == 0)
                ptop[wm + mi*16 + lg*4 + r][w & 1] = make_float2(bd, (float)bi);
        }
    __syncthreads();
    if (tid < 128){
        float2 hA = ptop[tid][0], hB = ptop[tid][1];
        int   gA = (int)hA.y, gB = (int)hB.y;
        bool takeB = (hB.x < hA.x) || (hB.x == hA.x && gB < gA);
        partials[(size_t)(m0 + tid)*4 + blockIdx.y] = takeB ? hB : hA;
    }
}

// ---------------------------------------------------------------------------
// Token + commitment: min over 4 (d,idx) partials, zz from zz_out.
// ---------------------------------------------------------------------------
__global__ __launch_bounds__(256) void token_reduce(
    const float* __restrict__ zz_out, const float2* __restrict__ partials,
    float* __restrict__ tokf, float* __restrict__ loss)
{
    const int tid = threadIdx.x;
    const int row = blockIdx.x*256 + tid;
    float2 p0 = partials[(size_t)row*4 + 0];
    float2 p1 = partials[(size_t)row*4 + 1];
    float2 p2 = partials[(size_t)row*4 + 2];
    float2 p3 = partials[(size_t)row*4 + 3];
    float d = p0.x; int g = (int)p0.y;
    if (p1.x < d || (p1.x == d && (int)p1.y < g)){ d = p1.x; g = (int)p1.y; }
    if (p2.x < d || (p2.x == d && (int)p2.y < g)){ d = p2.x; g = (int)p2.y; }
    if (p3.x < d || (p3.x == d && (int)p3.y < g)){ d = p3.x; g = (int)p3.y; }
    tokf[row] = (float)g;
    float cs = zz_out[row] + d;
    #pragma unroll
    for (int m=1; m<64; m<<=1) cs += __shfl_xor(cs, m);
    __shared__ float wsum[4];
    const int lane = tid & 63, w = tid >> 6;
    if (lane == 0) wsum[w] = cs;
    __syncthreads();
    if (tid == 0) atomicAdd(loss + 1, wsum[0]+wsum[1]+wsum[2]+wsum[3]);
}

// ---------------------------------------------------------------------------
// bf16 MFMA GEMM (decoder tables): Y[M,256] = gelu(A @ W^T + b), M=512.
// ---------------------------------------------------------------------------
__global__ __launch_bounds__(256) void mfma_gemm(
    const ushort* __restrict__ Abf,
    const ushort* __restrict__ Wbf,
    const float* __restrict__ bias,
    ushort* __restrict__ Ybf)
{
    __shared__ __align__(16) ushort Al[128][40];
    __shared__ __align__(16) ushort Wl[128][40];

    const int tid = threadIdx.x;
    const int m0 = blockIdx.x * 128;
    const int n0 = blockIdx.y * 128;
    const int srow = tid >> 1, shalf = (tid & 1) * 16;
    const int lane = tid & 63;
    const int w = tid >> 6;
    const int wm = (w >> 1) * 64, wn = (w & 1) * 64;
    const int lr = lane & 15, lg = lane >> 4;

    const ushort* asrc = Abf + (size_t)(m0 + srow)*256 + shalf;
    const ushort* wsrc = Wbf + (size_t)(n0 + srow)*256 + shalf;

    f32x4 acc[4][4];
    #pragma unroll
    for (int mi=0;mi<4;++mi)
        #pragma unroll
        for (int ni=0;ni<4;++ni)
            acc[mi][ni] = (f32x4){0.f,0.f,0.f,0.f};

    for (int k0=0; k0<256; k0+=32){
        *(uint4*)&Al[srow][shalf]   = *(const uint4*)(asrc + k0);
        *(uint4*)&Al[srow][shalf+8] = *(const uint4*)(asrc + k0 + 8);
        *(uint4*)&Wl[srow][shalf]   = *(const uint4*)(wsrc + k0);
        *(uint4*)&Wl[srow][shalf+8] = *(const uint4*)(wsrc + k0 + 8);
        __syncthreads();

        short8 af[4], bfr[4];
        #pragma unroll
        for (int mi=0;mi<4;++mi)
            af[mi] = *(const short8*)&Al[wm + mi*16 + lr][lg*8];
        #pragma unroll
        for (int ni=0;ni<4;++ni)
            bfr[ni] = *(const short8*)&Wl[wn + ni*16 + lr][lg*8];
        #pragma unroll
        for (int mi=0;mi<4;++mi)
            #pragma unroll
            for (int ni=0;ni<4;++ni)
                acc[mi][ni] = __builtin_amdgcn_mfma_f32_16x16x32_bf16(
                    af[mi], bfr[ni], acc[mi][ni], 0, 0, 0);
        __syncthreads();
    }

    float bn[4];
    #pragma unroll
    for (int ni=0;ni<4;++ni) bn[ni] = bias[n0 + wn + ni*16 + lr];
    #pragma unroll
    for (int mi=0;mi<4;++mi)
        #pragma unroll
        for (int ni=0;ni<4;++ni)
            #pragma unroll
            for (int r=0;r<4;++r){
                int row = m0 + wm + mi*16 + lg*4 + r;
                float v = acc[mi][ni][r] + bn[ni];
                v = gelu_f(v);
                Ybf[(size_t)row*256 + n0 + wn + ni*16 + lr] = f2bf(v);
            }
}

// ---------------------------------------------------------------------------
// dec3 table: R[512][48] = L2 @ W3^T + b3 (W3 converted in-kernel).
// ---------------------------------------------------------------------------
__global__ __launch_bounds__(256) void dec3_table(
    const ushort* __restrict__ Ain, const float* __restrict__ W,
    const float* __restrict__ bias, float* __restrict__ Rt)
{
    __shared__ __align__(16) ushort Al[256][40];
    __shared__ __align__(16) ushort Wl[48][40];

    const int tid = threadIdx.x;
    const int m0 = blockIdx.x * 256;
    const int lane = tid & 63;
    const int w = tid >> 6;
    const int lr = lane & 15, lg = lane >> 4;

    const ushort* asrc = Ain + (size_t)(m0 + tid)*256;

    f32x4 acc[4][3];
    #pragma unroll
    for (int mi=0;mi<4;++mi)
        #pragma unroll
        for (int ni=0;ni<3;++ni)
            acc[mi][ni] = (f32x4){0.f,0.f,0.f,0.f};

    for (int k0=0; k0<256; k0+=32){
        *(uint4*)&Al[tid][0]  = *(const uint4*)(asrc + k0);
        *(uint4*)&Al[tid][8]  = *(const uint4*)(asrc + k0 + 8);
        *(uint4*)&Al[tid][16] = *(const uint4*)(asrc + k0 + 16);
        *(uint4*)&Al[tid][24] = *(const uint4*)(asrc + k0 + 24);
        if (tid < 96){
            const int wrow = tid >> 1, wh = (tid & 1)*16;
            const float* wp = W + (size_t)wrow*256 + k0 + wh;
            float4 f0 = *(const float4*)(wp);
            float4 f1 = *(const float4*)(wp+4);
            float4 f2 = *(const float4*)(wp+8);
            float4 f3 = *(const float4*)(wp+12);
            ushort t[16];
            t[0]=f2bf(f0.x); t[1]=f2bf(f0.y); t[2]=f2bf(f0.z); t[3]=f2bf(f0.w);
            t[4]=f2bf(f1.x); t[5]=f2bf(f1.y); t[6]=f2bf(f1.z); t[7]=f2bf(f1.w);
            t[8]=f2bf(f2.x); t[9]=f2bf(f2.y); t[10]=f2bf(f2.z); t[11]=f2bf(f2.w);
            t[12]=f2bf(f3.x); t[13]=f2bf(f3.y); t[14]=f2bf(f3.z); t[15]=f2bf(f3.w);
            *(uint4*)&Wl[wrow][wh]   = *(const uint4*)&t[0];
            *(uint4*)&Wl[wrow][wh+8] = *(const uint4*)&t[8];
        }
        __syncthreads();

        short8 bfr[3];
        #pragma unroll
        for (int ni=0;ni<3;++ni)
            bfr[ni] = *(const short8*)&Wl[ni*16 + lr][lg*8];
        #pragma unroll
        for (int mi=0;mi<4;++mi){
            short8 af = *(const short8*)&Al[w*64 + mi*16 + lr][lg*8];
            #pragma unroll
            for (int ni=0;ni<3;++ni)
                acc[mi][ni] = __builtin_amdgcn_mfma_f32_16x16x32_bf16(
                    af, bfr[ni], acc[mi][ni], 0, 0, 0);
        }
        __syncthreads();
    }

    #pragma unroll
    for (int ni=0;ni<3;++ni){
        const int col = ni*16 + lr;
        const float bn = bias[col];
        #pragma unroll
        for (int mi=0;mi<4;++mi)
            #pragma unroll
            for (int r=0;r<4;++r){
                int row = m0 + w*64 + mi*16 + lg*4 + r;
                Rt[row*48 + col] = acc[mi][ni][r] + bn;
            }
    }
}

// ---------------------------------------------------------------------------
// gather + unpatchify + recon loss: recon = unpatchify(R[tokens]).
// ---------------------------------------------------------------------------
__global__ __launch_bounds__(256) void gather_recon(
    const float* __restrict__ Rt, const float* __restrict__ tokf,
    const float* __restrict__ frames, float* __restrict__ recon,
    float* __restrict__ loss)
{
    const int tid = threadIdx.x;
    const int idx = blockIdx.x*256 + tid;
    const int p = idx >> 2, ph = idx & 3;
    const int g = (int)tokf[p];
    int b = p >> 12, nl = p & 4095, hh = nl >> 6, ww = nl & 63;
    size_t base = (size_t)(((b*256 + hh*4 + ph)*256 + ww*4)*3);
    const float* rp = Rt + g*48 + ph*12;
    const float sc = 2.0f/255.0f;
    float ls = 0.0f;
    #pragma unroll
    for (int j=0;j<3;++j){
        float4 y = *(const float4*)(rp + j*4);
        float4 f = *(const float4*)(frames + base + j*4);
        float t0=f.x*sc-1.0f, t1=f.y*sc-1.0f, t2=f.z*sc-1.0f, t3=f.w*sc-1.0f;
        float d0=y.x-t0, d1=y.y-t1, d2=y.z-t2, d3=y.w-t3;
        ls += d0*d0 + d1*d1 + d2*d2 + d3*d3;
        *(float4*)(recon + base + j*4) = y;
    }
    #pragma unroll
    for (int off=32; off>0; off>>=1) ls += __shfl_down(ls, off);
    __shared__ float wsum[4];
    int lane = tid & 63, w = tid >> 6;
    if (lane == 0) wsum[w] = ls;
    __syncthreads();
    if (tid == 0) atomicAdd(loss + 0, wsum[0]+wsum[1]+wsum[2]+wsum[3]);
}

__global__ void finalize_kernel(float* __restrict__ loss){
    if (threadIdx.x == 0 && blockIdx.x == 0){
        loss[0] = loss[0] * (1.0f/6291456.0f);
        float c = loss[1] * (1.0f/33554432.0f);
        loss[1] = c;
        loss[2] = c;
    }
}

extern "C" void kernel_launch(void* const* d_in, const int* in_sizes, int n_in,
                              void* d_out, int out_size, void* d_ws, size_t ws_size,
                              hipStream_t stream)
{
    (void)in_sizes; (void)n_in; (void)out_size; (void)ws_size;
    const float* frames   = (const float*)d_in[0];
    const float* enc_w1   = (const float*)d_in[1];
    const float* enc_b1   = (const float*)d_in[2];
    const float* enc_w2   = (const float*)d_in[3];
    const float* enc_b2   = (const float*)d_in[4];
    const float* enc_w3   = (const float*)d_in[5];
    const float* enc_b3   = (const float*)d_in[6];
    const float* codebook = (const float*)d_in[7];
    const float* dec_w1   = (const float*)d_in[8];
    const float* dec_b1   = (const float*)d_in[9];
    const float* dec_w2   = (const float*)d_in[10];
    const float* dec_b2   = (const float*)d_in[11];
    const float* dec_w3   = (const float*)d_in[12];
    const float* dec_b3   = (const float*)d_in[13];

    // ws: exactly the proven 256 MiB: P (134 MB) + Q (134 MB)
    float* P = (float*)d_ws;                 // h1 f32 -> half z planes -> tables
    float* Q = P + (size_t)33554432;         // h2 f32 (alive through both zout halves)
    // half-row split planes inside dead P (3 x 33.5 MB = 100.6 MB < 134 MB)
    ushort* zb0 = (ushort*)P;
    ushort* zb1 = zb0 + (size_t)HROWS*256;
    ushort* zb2 = zb1 + (size_t)HROWS*256;
    // decoder tables (after tokens complete, planes dead)
    ushort* L1 = (ushort*)P;
    ushort* L2 = (ushort*)(P + 65536);
    float*  Rt = P + 131072;

    // outputs; recon region doubles as scratch (dead until gather_recon)
    float* recon = (float*)d_out;
    float* tokf  = recon + 6291456;
    float* loss  = tokf + 131072;
    float*  cn   = recon;
    ushort* cbb  = (ushort*)(recon + 512);
    ushort* w1b  = (ushort*)(recon + 66048);
    ushort* w2b  = (ushort*)(recon + 98816);
    ushort* w2s0 = (ushort*)(recon + 131584);
    ushort* w2s1 = (ushort*)(recon + 164352);
    ushort* w2s2 = (ushort*)(recon + 197120);
    ushort* w3s0 = (ushort*)(recon + 229888);
    ushort* w3s1 = (ushort*)(recon + 262656);
    ushort* w3s2 = (ushort*)(recon + 295424);
    ushort* cbs0 = (ushort*)(recon + 328192);
    ushort* cbs1 = (ushort*)(recon + 393728);
    ushort* cbs2 = (ushort*)(recon + 459264);
    float*  zzb  = recon + 524800;           // 131072 f32, ends 655872
    ushort* w1p0 = (ushort*)(recon + 655872);
    ushort* w1p1 = (ushort*)(recon + 664064);
    ushort* w1p2 = (ushort*)(recon + 672256);
    float*  bias2 = recon + 680448;          // ends 680704
    float2* partials = (float2*)(recon + 700416);  // 131072*4 float2, ends 1748992

    hipMemsetAsync(loss, 0, 3*sizeof(float), stream);

    dim3 blk(256);
    prep_kernel<<<dim3(209), blk, 0, stream>>>(enc_w2, enc_w3, dec_w1, dec_w2,
        enc_w1, enc_b1, codebook,
        w2s0, w2s1, w2s2, w3s0, w3s1, w3s2, w1b, w2b,
        cn, cbb, cbs0, cbs1, cbs2, w1p0, w1p1, w1p2, bias2);
    // encoder layers 1-2
    split6_gemm<64,  true, 1, true ><<<dim3(T_ROWS/64), blk, 0, stream>>>(nullptr, frames, w1p0, w1p1, w1p2, bias2, P);
    split6_gemm<256, true, 0, false><<<dim3(T_ROWS/64), blk, 0, stream>>>(P, nullptr, w2s0, w2s1, w2s2, enc_b2, Q);
    // enc3 + tokens, processed in two row-halves (planes fit in dead P)
    for (int h = 0; h < 2; ++h){
        const size_t roff = (size_t)h * HROWS;
        split6_zout<<<dim3(HROWS/64), blk, 0, stream>>>(
            Q + roff*256, w3s0, w3s1, w3s2, enc_b3, zb0, zb1, zb2, zzb + roff);
        tokens_split6_pp<<<dim3(HROWS/128, 4), blk, 0, stream>>>(
            zb0, zb1, zb2, cbs0, cbs1, cbs2, cn, partials + roff*4);
    }
    token_reduce<<<dim3(T_ROWS/256), blk, 0, stream>>>(zzb, partials, tokf, loss);
    // decoder: per-code tables, then gather
    mfma_gemm<<<dim3(4, 2), blk, 0, stream>>>(cbb, w1b, dec_b1, L1);
    mfma_gemm<<<dim3(4, 2), blk, 0, stream>>>(L1, w2b, dec_b2, L2);
    dec3_table<<<dim3(2), blk, 0, stream>>>(L2, dec_w3, dec_b3, Rt);
    gather_recon<<<dim3(T_ROWS*4/256), blk, 0, stream>>>(Rt, tokf, frames, recon, loss);
    finalize_kernel<<<dim3(1), dim3(64), 0, stream>>>(loss);
}

// Round 17
// 596.072 us; speedup vs baseline: 1.1910x; 1.1910x over previous
//
#include <hip/hip_runtime.h>
#include <hip/hip_bf16.h>
#include <math.h>
#include <float.h>
#include <limits.h>

#define T_ROWS 131072   // 32 * 4096 patches

typedef __attribute__((ext_vector_type(8))) short short8;
typedef __attribute__((ext_vector_type(4))) float f32x4;

__device__ __forceinline__ float gelu_f(float x){
    return 0.5f * x * (1.0f + erff(x * 0.7071067811865475f));
}
__device__ __forceinline__ ushort f2bf(float f){
    union { float f; unsigned int i; } v; v.f = f;
    unsigned int i = v.i;
    unsigned int r = (i + 0x7fffu + ((i >> 16) & 1u)) >> 16;
    return (ushort)r;
}
// exact 3-way truncation split: x ~= b0+b1+b2 (each bf16), >=24 mantissa bits
__device__ __forceinline__ void split3(float x, ushort &u0, ushort &u1, ushort &u2){
    union { float f; unsigned int i; } v; v.f = x;
    u0 = (ushort)(v.i >> 16);
    union { unsigned int i; float f; } h0; h0.i = ((unsigned int)u0) << 16;
    float r = x - h0.f;                       // exact (Sterbenz)
    union { float f; unsigned int i; } vr; vr.f = r;
    u1 = (ushort)(vr.i >> 16);
    union { unsigned int i; float f; } h1; h1.i = ((unsigned int)u1) << 16;
    float r2 = r - h1.f;                      // exact
    union { float f; unsigned int i; } v2; v2.f = r2;
    u2 = (ushort)(v2.i >> 16);
}

// ---------------------------------------------------------------------------
// Merged prep
// ---------------------------------------------------------------------------
__global__ __launch_bounds__(256) void prep_kernel(
    const float* __restrict__ w2, const float* __restrict__ w3,
    const float* __restrict__ d1, const float* __restrict__ d2,
    const float* __restrict__ w1, const float* __restrict__ b1,
    const float* __restrict__ cb,
    ushort* __restrict__ w2s0, ushort* __restrict__ w2s1, ushort* __restrict__ w2s2,
    ushort* __restrict__ w3s0, ushort* __restrict__ w3s1, ushort* __restrict__ w3s2,
    ushort* __restrict__ w1b, ushort* __restrict__ w2b,
    float* __restrict__ cn, ushort* __restrict__ cbb,
    ushort* __restrict__ cbs0, ushort* __restrict__ cbs1, ushort* __restrict__ cbs2,
    ushort* __restrict__ w1p0, ushort* __restrict__ w1p1, ushort* __restrict__ w1p2,
    float* __restrict__ bias2)
{
    const int blk = blockIdx.x, tid = threadIdx.x;
    if (blk < 64){
        const int i = (blk*256 + tid)*4;
        float4 a = *(const float4*)(w2 + i);
        ushort4 s0, s1, s2;
        split3(a.x, s0.x, s1.x, s2.x); split3(a.y, s0.y, s1.y, s2.y);
        split3(a.z, s0.z, s1.z, s2.z); split3(a.w, s0.w, s1.w, s2.w);
        *(ushort4*)(w2s0+i)=s0; *(ushort4*)(w2s1+i)=s1; *(ushort4*)(w2s2+i)=s2;
        float4 b = *(const float4*)(w3 + i);
        split3(b.x, s0.x, s1.x, s2.x); split3(b.y, s0.y, s1.y, s2.y);
        split3(b.z, s0.z, s1.z, s2.z); split3(b.w, s0.w, s1.w, s2.w);
        *(ushort4*)(w3s0+i)=s0; *(ushort4*)(w3s1+i)=s1; *(ushort4*)(w3s2+i)=s2;
        float4 c = *(const float4*)(d1 + i);
        ushort4 u; u.x=f2bf(c.x); u.y=f2bf(c.y); u.z=f2bf(c.z); u.w=f2bf(c.w);
        *(ushort4*)(w1b+i) = u;
        float4 d = *(const float4*)(d2 + i);
        u.x=f2bf(d.x); u.y=f2bf(d.y); u.z=f2bf(d.z); u.w=f2bf(d.w);
        *(ushort4*)(w2b+i) = u;
    } else if (blk < 192){
        const int lane = tid & 63;
        const int code = (blk-64)*4 + (tid >> 6);
        float4 v = ((const float4*)(cb + (size_t)code*256))[lane];
        size_t off = (size_t)code*256 + lane*4;
        ushort4 u; u.x=f2bf(v.x); u.y=f2bf(v.y); u.z=f2bf(v.z); u.w=f2bf(v.w);
        *(ushort4*)(cbb + off) = u;
        ushort4 s0, s1, s2;
        split3(v.x, s0.x, s1.x, s2.x); split3(v.y, s0.y, s1.y, s2.y);
        split3(v.z, s0.z, s1.z, s2.z); split3(v.w, s0.w, s1.w, s2.w);
        *(ushort4*)(cbs0 + off) = s0;
        *(ushort4*)(cbs1 + off) = s1;
        *(ushort4*)(cbs2 + off) = s2;
        float s = v.x*v.x + v.y*v.y + v.z*v.z + v.w*v.w;
        #pragma unroll
        for (int m=1; m<64; m<<=1) s += __shfl_xor(s, m);
        if (lane == 0) cn[code] = s;
    } else if (blk < 208){
        const int idx = (blk-192)*256 + tid;    // 0..4095
        const int n = idx >> 4, k = (idx & 15)*4;
        ushort4 s0 = {0,0,0,0}, s1 = {0,0,0,0}, s2 = {0,0,0,0};
        if (k < 48){
            float4 v = *(const float4*)(w1 + n*48 + k);
            split3(v.x, s0.x, s1.x, s2.x); split3(v.y, s0.y, s1.y, s2.y);
            split3(v.z, s0.z, s1.z, s2.z); split3(v.w, s0.w, s1.w, s2.w);
        }
        *(ushort4*)(w1p0 + n*64 + k) = s0;
        *(ushort4*)(w1p1 + n*64 + k) = s1;
        *(ushort4*)(w1p2 + n*64 + k) = s2;
    } else {
        float s = 0.0f;
        for (int k=0;k<48;++k) s += w1[tid*48 + k];
        bias2[tid] = b1[tid] - s;
    }
}

// ---------------------------------------------------------------------------
// f32-faithful split6 MFMA GEMM, 64 rows x 256 cols per block (A read ONCE).
// ---------------------------------------------------------------------------
template<int KTOT, bool GELU, int LOADER, bool SCALE>
__global__ __launch_bounds__(256, 3) void split6_gemm(
    const float* __restrict__ Ain,
    const float* __restrict__ frames,
    const ushort* __restrict__ W0, const ushort* __restrict__ W1,
    const ushort* __restrict__ W2,
    const float* __restrict__ bias,
    float* __restrict__ Cout)
{
    __shared__ __align__(16) ushort Al[3][64][40];
    __shared__ __align__(16) ushort Wl[256][40];

    const int tid = threadIdx.x;
    const int m0 = blockIdx.x * 64;
    const int arow = tid >> 2, q = tid & 3;
    const int lane = tid & 63;
    const int w = tid >> 6;
    const int lr = lane & 15, lg = lane >> 4;

    const float* asrc = nullptr;
    int pbase = 0;
    if constexpr (LOADER == 0){
        asrc = Ain + (size_t)(m0 + arow)*KTOT + q*8;
    } else {
        int p = m0 + arow;
        int b = p >> 12, nl = p & 4095, hh = nl >> 6, ww = nl & 63;
        pbase = ((b*256 + hh*4)*256 + ww*4)*3;
    }
    const ushort* wsrc  = W0 + (size_t)tid*KTOT;
    const ushort* w1frag = W1 + (size_t)(w*64 + lr)*KTOT + lg*8;
    const ushort* w2frag = W2 + (size_t)(w*64 + lr)*KTOT + lg*8;

    f32x4 acc[4][4];
    #pragma unroll
    for (int mi=0;mi<4;++mi)
        #pragma unroll
        for (int ni=0;ni<4;++ni)
            acc[mi][ni] = (f32x4){0.f,0.f,0.f,0.f};

    for (int k0=0; k0<KTOT; k0+=32){
        float x[8];
        if constexpr (LOADER == 0){
            *(float4*)&x[0] = *(const float4*)(asrc + k0);
            *(float4*)&x[4] = *(const float4*)(asrc + k0 + 4);
        } else {
            #pragma unroll
            for (int j=0;j<2;++j){
                int kk = k0 + q*8 + j*4;
                float4 v = {0.f,0.f,0.f,0.f};
                if (kk < 48){
                    int ph = kk/12, rem = kk - ph*12;
                    v = *(const float4*)(frames + pbase + ph*768 + rem);
                }
                x[j*4+0]=v.x; x[j*4+1]=v.y; x[j*4+2]=v.z; x[j*4+3]=v.w;
            }
        }
        ushort t0[8], t1[8], t2[8];
        #pragma unroll
        for (int e=0;e<8;++e) split3(x[e], t0[e], t1[e], t2[e]);
        *(uint4*)&Al[0][arow][q*8] = *(const uint4*)t0;
        *(uint4*)&Al[1][arow][q*8] = *(const uint4*)t1;
        *(uint4*)&Al[2][arow][q*8] = *(const uint4*)t2;
        *(uint4*)&Wl[tid][0]  = *(const uint4*)(wsrc + k0);
        *(uint4*)&Wl[tid][8]  = *(const uint4*)(wsrc + k0 + 8);
        *(uint4*)&Wl[tid][16] = *(const uint4*)(wsrc + k0 + 16);
        *(uint4*)&Wl[tid][24] = *(const uint4*)(wsrc + k0 + 24);
        short8 b1v[4], b2v[4];
        #pragma unroll
        for (int ni=0;ni<4;++ni){
            b1v[ni] = *(const short8*)(w1frag + (size_t)ni*16*KTOT + k0);
            b2v[ni] = *(const short8*)(w2frag + (size_t)ni*16*KTOT + k0);
        }
        __syncthreads();

        short8 b0v[4];
        #pragma unroll
        for (int ni=0;ni<4;++ni)
            b0v[ni] = *(const short8*)&Wl[w*64 + ni*16 + lr][lg*8];
        #pragma unroll
        for (int mi=0;mi<4;++mi){
            short8 a0 = *(const short8*)&Al[0][mi*16 + lr][lg*8];
            short8 a1 = *(const short8*)&Al[1][mi*16 + lr][lg*8];
            short8 a2 = *(const short8*)&Al[2][mi*16 + lr][lg*8];
            #pragma unroll
            for (int ni=0;ni<4;++ni)
                acc[mi][ni] = __builtin_amdgcn_mfma_f32_16x16x32_bf16(a0, b0v[ni], acc[mi][ni], 0,0,0);
            #pragma unroll
            for (int ni=0;ni<4;++ni)
                acc[mi][ni] = __builtin_amdgcn_mfma_f32_16x16x32_bf16(a0, b1v[ni], acc[mi][ni], 0,0,0);
            #pragma unroll
            for (int ni=0;ni<4;++ni)
                acc[mi][ni] = __builtin_amdgcn_mfma_f32_16x16x32_bf16(a1, b0v[ni], acc[mi][ni], 0,0,0);
            #pragma unroll
            for (int ni=0;ni<4;++ni)
                acc[mi][ni] = __builtin_amdgcn_mfma_f32_16x16x32_bf16(a0, b2v[ni], acc[mi][ni], 0,0,0);
            #pragma unroll
            for (int ni=0;ni<4;++ni)
                acc[mi][ni] = __builtin_amdgcn_mfma_f32_16x16x32_bf16(a1, b1v[ni], acc[mi][ni], 0,0,0);
            #pragma unroll
            for (int ni=0;ni<4;++ni)
                acc[mi][ni] = __builtin_amdgcn_mfma_f32_16x16x32_bf16(a2, b0v[ni], acc[mi][ni], 0,0,0);
        }
        __syncthreads();
    }

    const float alpha = 2.0f/255.0f;
    float bn[4];
    #pragma unroll
    for (int ni=0;ni<4;++ni) bn[ni] = bias[w*64 + ni*16 + lr];
    #pragma unroll
    for (int mi=0;mi<4;++mi)
        #pragma unroll
        for (int ni=0;ni<4;++ni)
            #pragma unroll
            for (int r=0;r<4;++r){
                int row = m0 + mi*16 + lg*4 + r;
                float v;
                if (SCALE) v = fmaf(alpha, acc[mi][ni][r], bn[ni]);
                else       v = acc[mi][ni][r] + bn[ni];
                if (GELU) v = gelu_f(v);
                Cout[(size_t)row*256 + w*64 + ni*16 + lr] = v;
            }
}

#define INSERT1(dv, iv) do { \
    float _d = (dv); int _i = (iv); \
    if (_d < bd || (_d == bd && _i < bi)){ bd = _d; bi = _i; } \
} while(0)

// ---------------------------------------------------------------------------
// EXACT distance pass via 6-term split-bf16 MFMA (proven config).
// ---------------------------------------------------------------------------
__global__ __launch_bounds__(256, 3) void tokens_split6(
    const float* __restrict__ Zf,
    const ushort* __restrict__ C0, const ushort* __restrict__ C1,
    const ushort* __restrict__ C2,
    const float* __restrict__ cn,
    float2* __restrict__ partials,
    float* __restrict__ zz_out)
{
    __shared__ __align__(16) ushort Al[3][128][40];
    __shared__ __align__(16) ushort Wl[2][128][40];
    __shared__ float2 ptop[128][2];

    const int tid = threadIdx.x;
    const int m0 = blockIdx.x * 128;
    const int n0 = blockIdx.y * 128;
    const int srow = tid >> 1, shalf = (tid & 1) * 16;
    const int lane = tid & 63;
    const int w = tid >> 6;
    const int wm = (w >> 1) * 64, wn = (w & 1) * 64;
    const int lr = lane & 15, lg = lane >> 4;

    const float*  asrc = Zf + (size_t)(m0 + srow)*256 + shalf;
    const ushort* ws0  = C0 + (size_t)(n0 + srow)*256 + shalf;
    const ushort* ws1  = C1 + (size_t)(n0 + srow)*256 + shalf;
    const ushort* c2frag = C2 + (size_t)(n0 + wn + lr)*256 + lg*8;

    f32x4 acc[4][4];
    #pragma unroll
    for (int mi=0;mi<4;++mi)
        #pragma unroll
        for (int ni=0;ni<4;++ni)
            acc[mi][ni] = (f32x4){0.f,0.f,0.f,0.f};

    float zzp = 0.0f;

    for (int k0=0; k0<256; k0+=32){
        float x[16];
        *(float4*)&x[0]  = *(const float4*)(asrc + k0);
        *(float4*)&x[4]  = *(const float4*)(asrc + k0 + 4);
        *(float4*)&x[8]  = *(const float4*)(asrc + k0 + 8);
        *(float4*)&x[12] = *(const float4*)(asrc + k0 + 12);
        ushort t0[16], t1[16], t2[16];
        #pragma unroll
        for (int e=0;e<16;++e){
            split3(x[e], t0[e], t1[e], t2[e]);
            zzp = fmaf(x[e], x[e], zzp);
        }
        *(uint4*)&Al[0][srow][shalf]   = *(const uint4*)&t0[0];
        *(uint4*)&Al[0][srow][shalf+8] = *(const uint4*)&t0[8];
        *(uint4*)&Al[1][srow][shalf]   = *(const uint4*)&t1[0];
        *(uint4*)&Al[1][srow][shalf+8] = *(const uint4*)&t1[8];
        *(uint4*)&Al[2][srow][shalf]   = *(const uint4*)&t2[0];
        *(uint4*)&Al[2][srow][shalf+8] = *(const uint4*)&t2[8];
        *(uint4*)&Wl[0][srow][shalf]   = *(const uint4*)(ws0 + k0);
        *(uint4*)&Wl[0][srow][shalf+8] = *(const uint4*)(ws0 + k0 + 8);
        *(uint4*)&Wl[1][srow][shalf]   = *(const uint4*)(ws1 + k0);
        *(uint4*)&Wl[1][srow][shalf+8] = *(const uint4*)(ws1 + k0 + 8);
        short8 b2[4];
        #pragma unroll
        for (int ni=0;ni<4;++ni)
            b2[ni] = *(const short8*)(c2frag + (size_t)ni*16*256 + k0);
        __syncthreads();

        short8 b0[4], b1[4];
        #pragma unroll
        for (int ni=0;ni<4;++ni){
            b0[ni] = *(const short8*)&Wl[0][wn + ni*16 + lr][lg*8];
            b1[ni] = *(const short8*)&Wl[1][wn + ni*16 + lr][lg*8];
        }
        #pragma unroll
        for (int mi=0;mi<4;++mi){
            short8 a0 = *(const short8*)&Al[0][wm + mi*16 + lr][lg*8];
            short8 a1 = *(const short8*)&Al[1][wm + mi*16 + lr][lg*8];
            short8 a2 = *(const short8*)&Al[2][wm + mi*16 + lr][lg*8];
            #pragma unroll
            for (int ni=0;ni<4;++ni)
                acc[mi][ni] = __builtin_amdgcn_mfma_f32_16x16x32_bf16(a0, b0[ni], acc[mi][ni], 0,0,0);
            #pragma unroll
            for (int ni=0;ni<4;++ni)
                acc[mi][ni] = __builtin_amdgcn_mfma_f32_16x16x32_bf16(a0, b1[ni], acc[mi][ni], 0,0,0);
            #pragma unroll
            for (int ni=0;ni<4;++ni)
                acc[mi][ni] = __builtin_amdgcn_mfma_f32_16x16x32_bf16(a1, b0[ni], acc[mi][ni], 0,0,0);
            #pragma unroll
            for (int ni=0;ni<4;++ni)
                acc[mi][ni] = __builtin_amdgcn_mfma_f32_16x16x32_bf16(a0, b2[ni], acc[mi][ni], 0,0,0);
            #pragma unroll
            for (int ni=0;ni<4;++ni)
                acc[mi][ni] = __builtin_amdgcn_mfma_f32_16x16x32_bf16(a1, b1[ni], acc[mi][ni], 0,0,0);
            #pragma unroll
            for (int ni=0;ni<4;++ni)
                acc[mi][ni] = __builtin_amdgcn_mfma_f32_16x16x32_bf16(a2, b0[ni], acc[mi][ni], 0,0,0);
        }
        __syncthreads();
    }

    // ||z||^2 per row: pair-combine the two k-halves (tid even/odd same row)
    {
        float other = __shfl_xor(zzp, 1);
        if (blockIdx.y == 0 && (tid & 1) == 0)
            zz_out[m0 + srow] = zzp + other;
    }

    float cnl[4];
    #pragma unroll
    for (int ni=0;ni<4;++ni) cnl[ni] = cn[n0 + wn + ni*16 + lr];

    #pragma unroll
    for (int mi=0;mi<4;++mi)
        #pragma unroll
        for (int r=0;r<4;++r){
            float bd = FLT_MAX; int bi = INT_MAX;
            #pragma unroll
            for (int ni=0;ni<4;++ni){
                float d = cnl[ni] - 2.0f*acc[mi][ni][r];
                int col = n0 + wn + ni*16 + lr;
                INSERT1(d, col);
            }
            #pragma unroll
            for (int m=1; m<16; m<<=1){
                float od = __shfl_xor(bd, m);
                int   oi = __shfl_xor(bi, m);
                INSERT1(od, oi);
            }
            if (lr == 0)
                ptop[wm + mi*16 + lg*4 + r][w & 1] = make_float2(bd, (float)bi);
        }
    __syncthreads();
    if (tid < 128){
        float2 hA = ptop[tid][0], hB = ptop[tid][1];
        int   gA = (int)hA.y, gB = (int)hB.y;
        bool takeB = (hB.x < hA.x) || (hB.x == hA.x && gB < gA);
        partials[(size_t)(m0 + tid)*4 + blockIdx.y] = takeB ? hB : hA;
    }
}

// ---------------------------------------------------------------------------
// Token + commitment: min over 4 (d,idx) partials, zz from zz_out.
// ---------------------------------------------------------------------------
__global__ __launch_bounds__(256) void token_reduce(
    const float* __restrict__ zz_out, const float2* __restrict__ partials,
    float* __restrict__ tokf, float* __restrict__ loss)
{
    const int tid = threadIdx.x;
    const int row = blockIdx.x*256 + tid;
    float2 p0 = partials[(size_t)row*4 + 0];
    float2 p1 = partials[(size_t)row*4 + 1];
    float2 p2 = partials[(size_t)row*4 + 2];
    float2 p3 = partials[(size_t)row*4 + 3];
    float d = p0.x; int g = (int)p0.y;
    if (p1.x < d || (p1.x == d && (int)p1.y < g)){ d = p1.x; g = (int)p1.y; }
    if (p2.x < d || (p2.x == d && (int)p2.y < g)){ d = p2.x; g = (int)p2.y; }
    if (p3.x < d || (p3.x == d && (int)p3.y < g)){ d = p3.x; g = (int)p3.y; }
    tokf[row] = (float)g;
    float cs = zz_out[row] + d;
    #pragma unroll
    for (int m=1; m<64; m<<=1) cs += __shfl_xor(cs, m);
    __shared__ float wsum[4];
    const int lane = tid & 63, w = tid >> 6;
    if (lane == 0) wsum[w] = cs;
    __syncthreads();
    if (tid == 0) atomicAdd(loss + 1, wsum[0]+wsum[1]+wsum[2]+wsum[3]);
}

// ---------------------------------------------------------------------------
// bf16 MFMA GEMM (decoder tables): Y[M,256] = gelu(A @ W^T + b), M=512.
// ---------------------------------------------------------------------------
__global__ __launch_bounds__(256) void mfma_gemm(
    const ushort* __restrict__ Abf,
    const ushort* __restrict__ Wbf,
    const float* __restrict__ bias,
    ushort* __restrict__ Ybf)
{
    __shared__ __align__(16) ushort Al[128][40];
    __shared__ __align__(16) ushort Wl[128][40];

    const int tid = threadIdx.x;
    const int m0 = blockIdx.x * 128;
    const int n0 = blockIdx.y * 128;
    const int srow = tid >> 1, shalf = (tid & 1) * 16;
    const int lane = tid & 63;
    const int w = tid >> 6;
    const int wm = (w >> 1) * 64, wn = (w & 1) * 64;
    const int lr = lane & 15, lg = lane >> 4;

    const ushort* asrc = Abf + (size_t)(m0 + srow)*256 + shalf;
    const ushort* wsrc = Wbf + (size_t)(n0 + srow)*256 + shalf;

    f32x4 acc[4][4];
    #pragma unroll
    for (int mi=0;mi<4;++mi)
        #pragma unroll
        for (int ni=0;ni<4;++ni)
            acc[mi][ni] = (f32x4){0.f,0.f,0.f,0.f};

    for (int k0=0; k0<256; k0+=32){
        *(uint4*)&Al[srow][shalf]   = *(const uint4*)(asrc + k0);
        *(uint4*)&Al[srow][shalf+8] = *(const uint4*)(asrc + k0 + 8);
        *(uint4*)&Wl[srow][shalf]   = *(const uint4*)(wsrc + k0);
        *(uint4*)&Wl[srow][shalf+8] = *(const uint4*)(wsrc + k0 + 8);
        __syncthreads();

        short8 af[4], bfr[4];
        #pragma unroll
        for (int mi=0;mi<4;++mi)
            af[mi] = *(const short8*)&Al[wm + mi*16 + lr][lg*8];
        #pragma unroll
        for (int ni=0;ni<4;++ni)
            bfr[ni] = *(const short8*)&Wl[wn + ni*16 + lr][lg*8];
        #pragma unroll
        for (int mi=0;mi<4;++mi)
            #pragma unroll
            for (int ni=0;ni<4;++ni)
                acc[mi][ni] = __builtin_amdgcn_mfma_f32_16x16x32_bf16(
                    af[mi], bfr[ni], acc[mi][ni], 0, 0, 0);
        __syncthreads();
    }

    float bn[4];
    #pragma unroll
    for (int ni=0;ni<4;++ni) bn[ni] = bias[n0 + wn + ni*16 + lr];
    #pragma unroll
    for (int mi=0;mi<4;++mi)
        #pragma unroll
        for (int ni=0;ni<4;++ni)
            #pragma unroll
            for (int r=0;r<4;++r){
                int row = m0 + wm + mi*16 + lg*4 + r;
                float v = acc[mi][ni][r] + bn[ni];
                v = gelu_f(v);
                Ybf[(size_t)row*256 + n0 + wn + ni*16 + lr] = f2bf(v);
            }
}

// ---------------------------------------------------------------------------
// dec3 table: R[512][48] = L2 @ W3^T + b3 (W3 converted in-kernel).
// ---------------------------------------------------------------------------
__global__ __launch_bounds__(256) void dec3_table(
    const ushort* __restrict__ Ain, const float* __restrict__ W,
    const float* __restrict__ bias, float* __restrict__ Rt)
{
    __shared__ __align__(16) ushort Al[256][40];
    __shared__ __align__(16) ushort Wl[48][40];

    const int tid = threadIdx.x;
    const int m0 = blockIdx.x * 256;
    const int lane = tid & 63;
    const int w = tid >> 6;
    const int lr = lane & 15, lg = lane >> 4;

    const ushort* asrc = Ain + (size_t)(m0 + tid)*256;

    f32x4 acc[4][3];
    #pragma unroll
    for (int mi=0;mi<4;++mi)
        #pragma unroll
        for (int ni=0;ni<3;++ni)
            acc[mi][ni] = (f32x4){0.f,0.f,0.f,0.f};

    for (int k0=0; k0<256; k0+=32){
        *(uint4*)&Al[tid][0]  = *(const uint4*)(asrc + k0);
        *(uint4*)&Al[tid][8]  = *(const uint4*)(asrc + k0 + 8);
        *(uint4*)&Al[tid][16] = *(const uint4*)(asrc + k0 + 16);
        *(uint4*)&Al[tid][24] = *(const uint4*)(asrc + k0 + 24);
        if (tid < 96){
            const int wrow = tid >> 1, wh = (tid & 1)*16;
            const float* wp = W + (size_t)wrow*256 + k0 + wh;
            float4 f0 = *(const float4*)(wp);
            float4 f1 = *(const float4*)(wp+4);
            float4 f2 = *(const float4*)(wp+8);
            float4 f3 = *(const float4*)(wp+12);
            ushort t[16];
            t[0]=f2bf(f0.x); t[1]=f2bf(f0.y); t[2]=f2bf(f0.z); t[3]=f2bf(f0.w);
            t[4]=f2bf(f1.x); t[5]=f2bf(f1.y); t[6]=f2bf(f1.z); t[7]=f2bf(f1.w);
            t[8]=f2bf(f2.x); t[9]=f2bf(f2.y); t[10]=f2bf(f2.z); t[11]=f2bf(f2.w);
            t[12]=f2bf(f3.x); t[13]=f2bf(f3.y); t[14]=f2bf(f3.z); t[15]=f2bf(f3.w);
            *(uint4*)&Wl[wrow][wh]   = *(const uint4*)&t[0];
            *(uint4*)&Wl[wrow][wh+8] = *(const uint4*)&t[8];
        }
        __syncthreads();

        short8 bfr[3];
        #pragma unroll
        for (int ni=0;ni<3;++ni)
            bfr[ni] = *(const short8*)&Wl[ni*16 + lr][lg*8];
        #pragma unroll
        for (int mi=0;mi<4;++mi){
            short8 af = *(const short8*)&Al[w*64 + mi*16 + lr][lg*8];
            #pragma unroll
            for (int ni=0;ni<3;++ni)
                acc[mi][ni] = __builtin_amdgcn_mfma_f32_16x16x32_bf16(
                    af, bfr[ni], acc[mi][ni], 0, 0, 0);
        }
        __syncthreads();
    }

    #pragma unroll
    for (int ni=0;ni<3;++ni){
        const int col = ni*16 + lr;
        const float bn = bias[col];
        #pragma unroll
        for (int mi=0;mi<4;++mi)
            #pragma unroll
            for (int r=0;r<4;++r){
                int row = m0 + w*64 + mi*16 + lg*4 + r;
                Rt[row*48 + col] = acc[mi][ni][r] + bn;
            }
    }
}

// ---------------------------------------------------------------------------
// gather + unpatchify + recon loss: recon = unpatchify(R[tokens]).
// ---------------------------------------------------------------------------
__global__ __launch_bounds__(256) void gather_recon(
    const float* __restrict__ Rt, const float* __restrict__ tokf,
    const float* __restrict__ frames, float* __restrict__ recon,
    float* __restrict__ loss)
{
    const int tid = threadIdx.x;
    const int idx = blockIdx.x*256 + tid;
    const int p = idx >> 2, ph = idx & 3;
    const int g = (int)tokf[p];
    int b = p >> 12, nl = p & 4095, hh = nl >> 6, ww = nl & 63;
    size_t base = (size_t)(((b*256 + hh*4 + ph)*256 + ww*4)*3);
    const float* rp = Rt + g*48 + ph*12;
    const float sc = 2.0f/255.0f;
    float ls = 0.0f;
    #pragma unroll
    for (int j=0;j<3;++j){
        float4 y = *(const float4*)(rp + j*4);
        float4 f = *(const float4*)(frames + base + j*4);
        float t0=f.x*sc-1.0f, t1=f.y*sc-1.0f, t2=f.z*sc-1.0f, t3=f.w*sc-1.0f;
        float d0=y.x-t0, d1=y.y-t1, d2=y.z-t2, d3=y.w-t3;
        ls += d0*d0 + d1*d1 + d2*d2 + d3*d3;
        *(float4*)(recon + base + j*4) = y;
    }
    #pragma unroll
    for (int off=32; off>0; off>>=1) ls += __shfl_down(ls, off);
    __shared__ float wsum[4];
    int lane = tid & 63, w = tid >> 6;
    if (lane == 0) wsum[w] = ls;
    __syncthreads();
    if (tid == 0) atomicAdd(loss + 0, wsum[0]+wsum[1]+wsum[2]+wsum[3]);
}

__global__ void finalize_kernel(float* __restrict__ loss){
    if (threadIdx.x == 0 && blockIdx.x == 0){
        loss[0] = loss[0] * (1.0f/6291456.0f);
        float c = loss[1] * (1.0f/33554432.0f);
        loss[1] = c;
        loss[2] = c;
    }
}

extern "C" void kernel_launch(void* const* d_in, const int* in_sizes, int n_in,
                              void* d_out, int out_size, void* d_ws, size_t ws_size,
                              hipStream_t stream)
{
    (void)in_sizes; (void)n_in; (void)out_size; (void)ws_size;
    const float* frames   = (const float*)d_in[0];
    const float* enc_w1   = (const float*)d_in[1];
    const float* enc_b1   = (const float*)d_in[2];
    const float* enc_w2   = (const float*)d_in[3];
    const float* enc_b2   = (const float*)d_in[4];
    const float* enc_w3   = (const float*)d_in[5];
    const float* enc_b3   = (const float*)d_in[6];
    const float* codebook = (const float*)d_in[7];
    const float* dec_w1   = (const float*)d_in[8];
    const float* dec_b1   = (const float*)d_in[9];
    const float* dec_w2   = (const float*)d_in[10];
    const float* dec_b2   = (const float*)d_in[11];
    const float* dec_w3   = (const float*)d_in[12];
    const float* dec_b3   = (const float*)d_in[13];

    // workspace: two [T,256] f32 regions (proven 256 MiB)
    float* P = (float*)d_ws;                 // h1 -> z_e -> decoder tables
    float* Q = P + (size_t)33554432;         // h2
    float2* partials = (float2*)(Q + 18000000);  // 4 MB, disjoint
    ushort* L1 = (ushort*)P;                 // 512x256 bf16 (after tokens)
    ushort* L2 = (ushort*)(P + 65536);
    float*  Rt = P + 131072;

    // outputs; recon region doubles as scratch for small constants
    float* recon = (float*)d_out;
    float* tokf  = recon + 6291456;
    float* loss  = tokf + 131072;
    float*  cn   = recon;
    ushort* cbb  = (ushort*)(recon + 512);
    ushort* w1b  = (ushort*)(recon + 66048);
    ushort* w2b  = (ushort*)(recon + 98816);
    ushort* w2s0 = (ushort*)(recon + 131584);
    ushort* w2s1 = (ushort*)(recon + 164352);
    ushort* w2s2 = (ushort*)(recon + 197120);
    ushort* w3s0 = (ushort*)(recon + 229888);
    ushort* w3s1 = (ushort*)(recon + 262656);
    ushort* w3s2 = (ushort*)(recon + 295424);
    ushort* cbs0 = (ushort*)(recon + 328192);
    ushort* cbs1 = (ushort*)(recon + 393728);
    ushort* cbs2 = (ushort*)(recon + 459264);
    float*  zzb  = recon + 524800;
    ushort* w1p0 = (ushort*)(recon + 655872);
    ushort* w1p1 = (ushort*)(recon + 664064);
    ushort* w1p2 = (ushort*)(recon + 672256);
    float*  bias2 = recon + 680448;

    hipMemsetAsync(loss, 0, 3*sizeof(float), stream);

    dim3 blk(256);
    prep_kernel<<<dim3(209), blk, 0, stream>>>(enc_w2, enc_w3, dec_w1, dec_w2,
        enc_w1, enc_b1, codebook,
        w2s0, w2s1, w2s2, w3s0, w3s1, w3s2, w1b, w2b,
        cn, cbb, cbs0, cbs1, cbs2, w1p0, w1p1, w1p2, bias2);
    // encoder: all three layers f32-faithful split6 MFMA
    split6_gemm<64,  true, 1, true ><<<dim3(T_ROWS/64), blk, 0, stream>>>(nullptr, frames, w1p0, w1p1, w1p2, bias2, P);
    split6_gemm<256, true, 0, false><<<dim3(T_ROWS/64), blk, 0, stream>>>(P, nullptr, w2s0, w2s1, w2s2, enc_b2, Q);
    split6_gemm<256, false,0, false><<<dim3(T_ROWS/64), blk, 0, stream>>>(Q, nullptr, w3s0, w3s1, w3s2, enc_b3, P);
    // vector quantization: EXACT split6 distances + reduce
    tokens_split6<<<dim3(T_ROWS/128, 4), blk, 0, stream>>>(P, cbs0, cbs1, cbs2, cn, partials, zzb);
    token_reduce<<<dim3(T_ROWS/256), blk, 0, stream>>>(zzb, partials, tokf, loss);
    // decoder: per-code tables (512 rows), then gather
    mfma_gemm<<<dim3(4, 2), blk, 0, stream>>>(cbb, w1b, dec_b1, L1);
    mfma_gemm<<<dim3(4, 2), blk, 0, stream>>>(L1, w2b, dec_b2, L2);
    dec3_table<<<dim3(2), blk, 0, stream>>>(L2, dec_w3, dec_b3, Rt);
    gather_recon<<<dim3(T_ROWS*4/256), blk, 0, stream>>>(Rt, tokf, frames, recon, loss);
    finalize_kernel<<<dim3(1), dim3(64), 0, stream>>>(loss);
}